// Round 21
// baseline (80.024 us; speedup 1.0000x reference)
//
#include <hip/hip_runtime.h>

typedef __bf16 bf16;
typedef __bf16 bf16x4 __attribute__((ext_vector_type(4)));
typedef __bf16 bf16x8 __attribute__((ext_vector_type(8)));
typedef float  f32x4  __attribute__((ext_vector_type(4)));

#define SCALE 0.17677669529663687f   // 32^-0.5
#define LOG2E 1.4426950408889634f

// ws layout (bytes) — xwin eliminated
#define WQKVT_OFF 0         // bf16 [288][96] (q cols pre-scaled by SCALE*LOG2E)
#define WOUTT_OFF 55296     // bf16 [96][96] transposed
#define BIASC_OFF 73728     // f32 [3 h][4 ni][4 w][64 lane][4 e] C-frag layout (xLOG2E)

#define CBAR() asm volatile("" ::: "memory")

// 16-lane (DPP row) all-reduce; ctrl must be a compile-time constant.
template <int CTRL>
__device__ __forceinline__ float dpp_mv(float x) {
    return __int_as_float(__builtin_amdgcn_update_dpp(
        0, __float_as_int(x), CTRL, 0xF, 0xF, true));
}
__device__ __forceinline__ float row16_max(float m) {
    m = fmaxf(m, dpp_mv<0xB1>(m));   // quad_perm [1,0,3,2]
    m = fmaxf(m, dpp_mv<0x4E>(m));   // quad_perm [2,3,0,1]
    m = fmaxf(m, dpp_mv<0x124>(m));  // row_ror:4
    m = fmaxf(m, dpp_mv<0x128>(m));  // row_ror:8
    return m;
}
__device__ __forceinline__ float row16_sum(float s) {
    s += dpp_mv<0xB1>(s);
    s += dpp_mv<0x4E>(s);
    s += dpp_mv<0x124>(s);
    s += dpp_mv<0x128>(s);
    return s;
}

// ---- weight/bias prep only (tiny): 4 blocks x 512
__global__ __launch_bounds__(512)
void prep(const float* __restrict__ wqkv, const float* __restrict__ pos,
          const float* __restrict__ wout, bf16* __restrict__ wqkvT,
          bf16* __restrict__ woutT, float* __restrict__ biasC)
{
    int tid = blockIdx.x * 512 + threadIdx.x;
    const int stride = 4 * 512;
    for (int i = tid; i < 288 * 96; i += stride) {
        int n = i / 96, c = i % 96;
        float v = wqkv[c * 288 + n];
        if (n < 96) v *= SCALE * LOG2E;   // fold softmax log2e into Q
        wqkvT[i] = (bf16)v;
    }
    for (int i = tid; i < 96 * 96; i += stride) {
        int o = i / 96, c = i % 96;
        woutT[i] = (bf16)wout[c * 96 + o];
    }
    // biasC[h][ni][w][lane][e] at row=w*16+(lane>>4)*4+e, col=ni*16+(lane&15)
    for (int i = tid; i < 3 * 4 * 4 * 64 * 4; i += stride) {
        int e = i & 3, lane = (i >> 2) & 63, wv = (i >> 8) & 3, ni = (i >> 10) & 3, h = i >> 12;
        int row = wv * 16 + ((lane >> 4) << 2) + e;
        int col = ni * 16 + (lane & 15);
        float v;
        if (col >= 49) v = -1e30f;            // exp2(-huge) = 0
        else if (row >= 49) v = 0.f;
        else {
            int ridx = ((col / 7) - (row / 7) + 6) * 13 + ((col % 7) - (row % 7) + 6);
            v = pos[ridx * 3 + h] * LOG2E;    // fold log2e into bias
        }
        biasC[i] = v;
    }
}

// One block (4 waves) per window, fused staging. A-frags loaded up front;
// barrier B0.5 marks xs dead -> V C-frags write packed directly into the
// vt overlay. LDS 40448 B -> 4 blocks/CU. XCD swizzle blkId = b*64+ww*8+wh.
__global__ __launch_bounds__(256, 4)
void winattn(const float* __restrict__ x, const float* __restrict__ bout,
             const bf16* __restrict__ wqkvT, const bf16* __restrict__ woutT,
             const float* __restrict__ biasC, float* __restrict__ out)
{
    __shared__ __align__(16) unsigned char smem[40448];
    bf16* qall = (bf16*)(smem);          // [64][104]
    bf16* kall = (bf16*)(smem + 13312);  // [64][104]
    bf16* vt   = (bf16*)(smem + 26624);  // [96][72] (overlays xs after B0.5)
    bf16* xs   = (bf16*)(smem + 26624);  // [64][108] staged window (13824 B both)
    bf16* Ost  = (bf16*)(smem);          // overlay qall
    float* fin = (float*)(smem + 13312); // [64][101] f32, overlays kall+vt

    const int tid = threadIdx.x;
    const int w = tid >> 6, lane = tid & 63;
    const int lr = lane & 15, lk = lane >> 4;

    // ---- XCD write-combining decode
    const int blkraw = blockIdx.x;
    const int b  = blkraw >> 6;
    const int wh = blkraw & 7;
    const int ww = (blkraw >> 3) & 7;
    const int row0 = wh * 7, col0 = ww * 7;

    // ---- stage x window -> xs[64][108] bf16 (zeros in pad rows)
    {
        const int t = lane;
        const int c0 = w * 24;
        const bool valid = t < 49;
        const int tr = valid ? t / 7 : 0, tc = valid ? t % 7 : 0;
        const float* xp = x + ((size_t)(b * 96 + c0)) * 3136
                            + (row0 + tr) * 56 + col0 + tc;
        bf16* xw = &xs[t * 108 + c0];
#pragma unroll
        for (int j = 0; j < 24; ++j) {
            float v = xp[(size_t)j * 3136];
            xw[j] = (bf16)(valid ? v : 0.f);
        }
    }
    __syncthreads();   // B0: xs ready

    // ---- A-frags for all strips (only xs consumers)
    bf16x8 a[4][3];
#pragma unroll
    for (int mi = 0; mi < 4; ++mi)
#pragma unroll
        for (int k = 0; k < 3; ++k) {
            bf16x4 lo = *(const bf16x4*)&xs[(mi * 16 + lr) * 108 + k * 32 + lk * 8];
            bf16x4 hi = *(const bf16x4*)&xs[(mi * 16 + lr) * 108 + k * 32 + lk * 8 + 4];
            a[mi][k] = __builtin_shufflevector(lo, hi, 0, 1, 2, 3, 4, 5, 6, 7);
        }
    __syncthreads();   // B0.5: all xs reads done -> vt overlay is safe

    // ---- QKV: wave w owns ni = {w, w+4, w+8, w+12} (+ w+16 if w<2)
    {
        auto compute = [&](int ni, f32x4 (&acc)[4]) {
#pragma unroll
            for (int mi = 0; mi < 4; ++mi) acc[mi] = (f32x4){0.f, 0.f, 0.f, 0.f};
#pragma unroll
            for (int k = 0; k < 3; ++k) {
                bf16x8 bb = *(const bf16x8*)&wqkvT[(ni * 16 + lr) * 96 + k * 32 + lk * 8];
#pragma unroll
                for (int mi = 0; mi < 4; ++mi)
                    acc[mi] = __builtin_amdgcn_mfma_f32_16x16x32_bf16(a[mi][k], bb, acc[mi], 0, 0, 0);
            }
        };
        auto writeQ = [&](int ni, f32x4 (&acc)[4]) {
#pragma unroll
            for (int mi = 0; mi < 4; ++mi)
#pragma unroll
                for (int e = 0; e < 4; ++e)
                    qall[(mi * 16 + lk * 4 + e) * 104 + ni * 16 + lr] = (bf16)acc[mi][e];
        };
        auto writeK = [&](int ni, f32x4 (&acc)[4]) {
#pragma unroll
            for (int mi = 0; mi < 4; ++mi)
#pragma unroll
                for (int e = 0; e < 4; ++e)
                    kall[(mi * 16 + lk * 4 + e) * 104 + (ni - 6) * 16 + lr] = (bf16)acc[mi][e];
        };
        auto writeV = [&](int ni, f32x4 (&acc)[4]) {
            // C row = token mi*16+lk*4+e, col = ch ni*16+lr -> vt[ch][tok] packed
#pragma unroll
            for (int mi = 0; mi < 4; ++mi) {
                bf16x4 pk;
#pragma unroll
                for (int e = 0; e < 4; ++e) pk[e] = (bf16)acc[mi][e];
                *(bf16x4*)&vt[((ni - 12) * 16 + lr) * 72 + mi * 16 + lk * 4] = pk;
            }
        };

        f32x4 acc[4];
        compute(w, acc);       writeQ(w, acc);
        compute(w + 4, acc);   if (w < 2) writeQ(w + 4, acc); else writeK(w + 4, acc);
        compute(w + 8, acc);   writeK(w + 8, acc);
        compute(w + 12, acc);  writeV(w + 12, acc);
        if (w < 2) { compute(w + 16, acc); writeV(w + 16, acc); }
    }
    // prefetch head-0 bias C-frags (overlaps barrier)
    f32x4 bias0[4], bias1[4], bias2[4];
#pragma unroll
    for (int ni = 0; ni < 4; ++ni)
        bias0[ni] = *(const f32x4*)&biasC[(size_t)((0 * 4 + ni) * 4 + w) * 256 + lane * 4];
    __syncthreads();   // B1: Q/K/V visible

    // ---- read Q A-frags (own strip) before P overlays it
    bf16x8 qa[3];
#pragma unroll
    for (int h = 0; h < 3; ++h)
        qa[h] = *(const bf16x8*)&qall[(w * 16 + lr) * 104 + h * 32 + lk * 8];
    CBAR();   // in-order DS pipe handles the WAR vs Pw writes

    bf16* Pw = (bf16*)(smem + w * 3328);   // [16][72] inside own qall strip

    f32x4 oacc[3][2];
#pragma unroll
    for (int h = 0; h < 3; ++h)
#pragma unroll
        for (int ni = 0; ni < 2; ++ni) oacc[h][ni] = (f32x4){0.f, 0.f, 0.f, 0.f};

#pragma unroll
    for (int h = 0; h < 3; ++h) {
        // S' = (Q*log2e)@K^T + bias*log2e (bias is the C-operand)
        f32x4 sacc[4];
        const f32x4* bc = (h == 0) ? bias0 : (h == 1) ? bias1 : bias2;
#pragma unroll
        for (int ni = 0; ni < 4; ++ni) {
            bf16x8 kb = *(const bf16x8*)&kall[(ni * 16 + lr) * 104 + h * 32 + lk * 8];
            sacc[ni] = __builtin_amdgcn_mfma_f32_16x16x32_bf16(qa[h], kb, bc[ni], 0, 0, 0);
        }
        // prefetch next head's bias (covered by softmax+PV)
        if (h == 0) {
#pragma unroll
            for (int ni = 0; ni < 4; ++ni)
                bias1[ni] = *(const f32x4*)&biasC[(size_t)((1 * 4 + ni) * 4 + w) * 256 + lane * 4];
        } else if (h == 1) {
#pragma unroll
            for (int ni = 0; ni < 4; ++ni)
                bias2[ni] = *(const f32x4*)&biasC[(size_t)((2 * 4 + ni) * 4 + w) * 256 + lane * 4];
        }
        // softmax in base-2: p = exp2(s' - m'); DPP 16-lane all-reduce
#pragma unroll
        for (int e = 0; e < 4; ++e) {
            float s0 = sacc[0][e], s1 = sacc[1][e], s2 = sacc[2][e], s3 = sacc[3][e];
            float m = row16_max(fmaxf(fmaxf(s0, s1), fmaxf(s2, s3)));
            float p0 = exp2f(s0 - m), p1 = exp2f(s1 - m);
            float p2 = exp2f(s2 - m), p3 = exp2f(s3 - m);
            float s = row16_sum((p0 + p1) + (p2 + p3));
            float inv = __builtin_amdgcn_rcpf(s);
            int rl = lk * 4 + e;
            Pw[rl * 72 + lr]      = (bf16)(p0 * inv);
            Pw[rl * 72 + 16 + lr] = (bf16)(p1 * inv);
            Pw[rl * 72 + 32 + lr] = (bf16)(p2 * inv);
            Pw[rl * 72 + 48 + lr] = (bf16)(p3 * inv);
        }
        CBAR();
        // PV: Ostrip_h += Pstrip @ V_h
#pragma unroll
        for (int kk = 0; kk < 2; ++kk) {
            bf16x8 pa = *(const bf16x8*)&Pw[lr * 72 + kk * 32 + lk * 8];
#pragma unroll
            for (int ni = 0; ni < 2; ++ni) {
                bf16x8 vb = *(const bf16x8*)&vt[(h * 32 + ni * 16 + lr) * 72 + kk * 32 + lk * 8];
                oacc[h][ni] = __builtin_amdgcn_mfma_f32_16x16x32_bf16(pa, vb, oacc[h][ni], 0, 0, 0);
            }
        }
        CBAR();
    }

    // ---- O -> Ost (overlay qall, own strip only)
#pragma unroll
    for (int h = 0; h < 3; ++h)
#pragma unroll
        for (int ni = 0; ni < 2; ++ni)
#pragma unroll
            for (int e = 0; e < 4; ++e)
                Ost[(w * 16 + lk * 4 + e) * 104 + h * 32 + ni * 16 + lr]
                    = (bf16)oacc[h][ni][e];
    __syncthreads();   // B3: Ost visible; kall/vt dead -> fin overlay safe

    // ---- proj: wave w owns ni tiles {w, w+4 (w<2)}; all 4 row strips.
    {
        const int pcnt = (w < 2) ? 2 : 1;
#pragma unroll
        for (int j = 0; j < 2; ++j) {
            if (j < pcnt) {
                const int ni = w + j * 4;
                const float bo = bout[ni * 16 + lr];
                f32x4 pacc[4];
#pragma unroll
                for (int mi = 0; mi < 4; ++mi) pacc[mi] = (f32x4){0.f, 0.f, 0.f, 0.f};
#pragma unroll
                for (int k = 0; k < 3; ++k) {
                    bf16x8 wb = *(const bf16x8*)&woutT[(ni * 16 + lr) * 96 + k * 32 + lk * 8];
#pragma unroll
                    for (int mi = 0; mi < 4; ++mi) {
                        bf16x8 as = *(const bf16x8*)&Ost[(mi * 16 + lr) * 104 + k * 32 + lk * 8];
                        pacc[mi] = __builtin_amdgcn_mfma_f32_16x16x32_bf16(as, wb, pacc[mi], 0, 0, 0);
                    }
                }
#pragma unroll
                for (int mi = 0; mi < 4; ++mi)
#pragma unroll
                    for (int e = 0; e < 4; ++e)
                        fin[(mi * 16 + lk * 4 + e) * 101 + ni * 16 + lr] = pacc[mi][e] + bo;
            }
        }
    }
    __syncthreads();   // B4

    // ---- store [b, c, H, W]; t = lane fixed, channel marches
    {
        const int t = lane;
        if (t < 49) {
            const int off = (row0 + t / 7) * 56 + col0 + t % 7;
            float* ob = out + (size_t)(b * 96 + w * 24) * 3136 + off;
            const float* fr = fin + t * 101 + w * 24;
#pragma unroll
            for (int j = 0; j < 24; ++j)
                ob[(size_t)j * 3136] = fr[j];
        }
    }
}

extern "C" void kernel_launch(void* const* d_in, const int* in_sizes, int n_in,
                              void* d_out, int out_size, void* d_ws, size_t ws_size,
                              hipStream_t stream) {
    const float* x    = (const float*)d_in[0];
    const float* wqkv = (const float*)d_in[1];
    const float* pos  = (const float*)d_in[2];
    const float* wout = (const float*)d_in[3];
    const float* bout = (const float*)d_in[4];
    float* outp = (float*)d_out;

    bf16*  wqkvT = (bf16*)((char*)d_ws + WQKVT_OFF);
    bf16*  woutT = (bf16*)((char*)d_ws + WOUTT_OFF);
    float* biasC = (float*)((char*)d_ws + BIASC_OFF);

    prep<<<dim3(4), dim3(512), 0, stream>>>(wqkv, pos, wout, wqkvT, woutT, biasC);
    winattn<<<dim3(4096), dim3(256), 0, stream>>>(x, bout, wqkvT, woutT,
                                                  biasC, outp);
}